// Round 1
// baseline (1565.531 us; speedup 1.0000x reference)
//
#include <hip/hip_runtime.h>

#define N_NODES 100000
#define N_EDGES 1600000
#define D_FEAT  64
#define K_STEPS 8

__global__ void k_zero(int* __restrict__ p, int n) {
    int i = blockIdx.x * blockDim.x + threadIdx.x;
    if (i < n) p[i] = 0;
}

__global__ void k_hist(const int* __restrict__ dst, int* __restrict__ counts, int n) {
    int i = blockIdx.x * blockDim.x + threadIdx.x;
    if (i < n) atomicAdd(&counts[dst[i]], 1);
}

// Single-workgroup exclusive scan over N_NODES counts -> offsets[0..N], cursor[v]=offsets[v].
__global__ void k_scan(const int* __restrict__ counts, int* __restrict__ offsets,
                       int* __restrict__ cursor, int n) {
    __shared__ int sums[1024];
    int t = threadIdx.x;
    const int CH = (n + 1023) / 1024;
    int begin = t * CH;
    int end = begin + CH; if (end > n) end = n;
    int s = 0;
    for (int i = begin; i < end; ++i) s += counts[i];
    sums[t] = s;
    __syncthreads();
    // Hillis-Steele inclusive scan over 1024 partial sums
    for (int off = 1; off < 1024; off <<= 1) {
        int v = (t >= off) ? sums[t - off] : 0;
        __syncthreads();
        sums[t] += v;
        __syncthreads();
    }
    int running = (t == 0) ? 0 : sums[t - 1];
    for (int i = begin; i < end; ++i) {
        int c = counts[i];
        offsets[i] = running;
        cursor[i]  = running;
        running += c;
    }
    if (t == 1023) offsets[n] = running;   // == total edge count
}

__global__ void k_scatter(const int* __restrict__ src, const int* __restrict__ dst,
                          const float* __restrict__ w, int* __restrict__ cursor,
                          int* __restrict__ csr_src, float* __restrict__ csr_w, int n) {
    int i = blockIdx.x * blockDim.x + threadIdx.x;
    if (i < n) {
        int d = dst[i];
        int pos = atomicAdd(&cursor[d], 1);
        csr_src[pos] = src[i];
        csr_w[pos]   = w[i];
    }
}

// One wave (64 lanes) per node; lane = feature index. Pure gather + FMA.
__global__ void k_prop(const float* __restrict__ hin, float* __restrict__ hout,
                       const int* __restrict__ offsets,
                       const int* __restrict__ csr_src, const float* __restrict__ csr_w,
                       int n) {
    int gtid = blockIdx.x * blockDim.x + threadIdx.x;
    int node = gtid >> 6;
    int lane = threadIdx.x & 63;
    if (node >= n) return;
    int b = offsets[node];
    int e = offsets[node + 1];
    float acc = 0.f;
    for (int i = b; i < e; ++i) {
        int s   = csr_src[i];
        float w = csr_w[i];
        acc = fmaf(w, hin[(size_t)s * D_FEAT + lane], acc);
    }
    hout[(size_t)node * D_FEAT + lane] = acc;
}

extern "C" void kernel_launch(void* const* d_in, const int* in_sizes, int n_in,
                              void* d_out, int out_size, void* d_ws, size_t ws_size,
                              hipStream_t stream) {
    const float* x   = (const float*)d_in[0];
    const float* ew  = (const float*)d_in[1];
    const int*   src = (const int*)d_in[2];
    const int*   dst = (const int*)d_in[3];
    float* out = (float*)d_out;

    // Workspace layout (all 4-byte typed, ~39.6 MB total)
    float* hA      = (float*)d_ws;                       // N*D floats
    float* csr_w   = hA + (size_t)N_NODES * D_FEAT;      // E floats
    int*   csr_src = (int*)(csr_w + N_EDGES);            // E ints
    int*   offsets = csr_src + N_EDGES;                  // N+1 ints
    int*   cursor  = offsets + (N_NODES + 1);            // N ints
    int*   counts  = cursor + N_NODES;                   // N ints

    k_zero<<<(N_NODES + 255) / 256, 256, 0, stream>>>(counts, N_NODES);
    k_hist<<<(N_EDGES + 255) / 256, 256, 0, stream>>>(dst, counts, N_EDGES);
    k_scan<<<1, 1024, 0, stream>>>(counts, offsets, cursor, N_NODES);
    k_scatter<<<(N_EDGES + 255) / 256, 256, 0, stream>>>(src, dst, ew, cursor,
                                                         csr_src, csr_w, N_EDGES);

    const int prop_grid = (N_NODES * D_FEAT + 255) / 256;
    const float* in = x;
    for (int k = 0; k < K_STEPS; ++k) {
        float* o = ((k & 1) == 0) ? hA : out;   // k=7 (last) writes d_out
        k_prop<<<prop_grid, 256, 0, stream>>>(in, o, offsets, csr_src, csr_w, N_NODES);
        in = o;
    }
}

// Round 2
// 691.940 us; speedup vs baseline: 2.2625x; 2.2625x over previous
//
#include <hip/hip_runtime.h>

#define N_NODES 100000
#define N_EDGES 1600000
#define D_FEAT  64
#define K_STEPS 8
#define NB_SCAN ((N_NODES + 255) / 256)   // 391 scan blocks

__global__ void k_zero(int* __restrict__ p, int n) {
    int i = blockIdx.x * blockDim.x + threadIdx.x;
    if (i < n) p[i] = 0;
}

__global__ void k_hist(const int* __restrict__ dst, int* __restrict__ counts, int n) {
    int i = blockIdx.x * blockDim.x + threadIdx.x;
    if (i < n) atomicAdd(&counts[dst[i]], 1);
}

// Phase 1: per-block sum of 256 counts
__global__ void k_bsum(const int* __restrict__ counts, int* __restrict__ blockSums, int n) {
    __shared__ int ws[4];
    int t = threadIdx.x;
    int i = blockIdx.x * 256 + t;
    int c = (i < n) ? counts[i] : 0;
    for (int off = 32; off; off >>= 1) c += __shfl_down(c, off);
    if ((t & 63) == 0) ws[t >> 6] = c;
    __syncthreads();
    if (t == 0) blockSums[blockIdx.x] = ws[0] + ws[1] + ws[2] + ws[3];
}

// Phase 2: single block scans the 391 block sums -> exclusive blockPrefix, total -> offsets[N]
__global__ void k_sscan(const int* __restrict__ blockSums, int* __restrict__ blockPrefix,
                        int* __restrict__ offsets, int nb, int n) {
    __shared__ int sh[512];
    int t = threadIdx.x;
    int v = (t < nb) ? blockSums[t] : 0;
    sh[t] = v;
    __syncthreads();
    for (int off = 1; off < 512; off <<= 1) {
        int u = (t >= off) ? sh[t - off] : 0;
        __syncthreads();
        sh[t] += u;
        __syncthreads();
    }
    if (t < nb) blockPrefix[t] = sh[t] - v;   // exclusive
    if (t == 511) offsets[n] = sh[511];        // total == N_EDGES
}

// Phase 3: per-block exclusive scan of counts + block prefix -> offsets, cursor
__global__ void k_bscan(const int* __restrict__ counts, const int* __restrict__ blockPrefix,
                        int* __restrict__ offsets, int* __restrict__ cursor, int n) {
    __shared__ int sh[256];
    int t = threadIdx.x;
    int i = blockIdx.x * 256 + t;
    int c = (i < n) ? counts[i] : 0;
    sh[t] = c;
    __syncthreads();
    for (int off = 1; off < 256; off <<= 1) {
        int u = (t >= off) ? sh[t - off] : 0;
        __syncthreads();
        sh[t] += u;
        __syncthreads();
    }
    int excl = sh[t] - c + blockPrefix[blockIdx.x];
    if (i < n) { offsets[i] = excl; cursor[i] = excl; }
}

__global__ void k_scatter(const int* __restrict__ src, const int* __restrict__ dst,
                          const float* __restrict__ w, int* __restrict__ cursor,
                          int* __restrict__ csr_src, float* __restrict__ csr_w, int n) {
    int i = blockIdx.x * blockDim.x + threadIdx.x;
    if (i < n) {
        int d = dst[i];
        int pos = atomicAdd(&cursor[d], 1);
        csr_src[pos] = src[i];
        csr_w[pos]   = w[i];
    }
}

// One wave per node. Lane = (edge_slot eg=lane>>4, feat_group fl=lane&15).
// Each iteration: 4 edges in parallel, each lane gathers float4 (16B).
// Final: xor-reduce over eg (lanes ^16, ^32), lanes 0..15 write float4 row.
__global__ void k_prop(const float* __restrict__ hin, float* __restrict__ hout,
                       const int* __restrict__ offsets,
                       const int* __restrict__ csr_src, const float* __restrict__ csr_w,
                       int n) {
    int wave = (blockIdx.x * blockDim.x + threadIdx.x) >> 6;
    int lane = threadIdx.x & 63;
    if (wave >= n) return;
    int b = offsets[wave];
    int e = offsets[wave + 1];
    int eg = lane >> 4;        // edge slot 0..3
    int fl = lane & 15;        // feature group (4 floats each)
    float4 acc = make_float4(0.f, 0.f, 0.f, 0.f);
    for (int i = b + eg; i < e; i += 4) {
        int s   = csr_src[i];
        float w = csr_w[i];
        const float4 v = *reinterpret_cast<const float4*>(&hin[((size_t)s << 6) + (fl << 2)]);
        acc.x = fmaf(w, v.x, acc.x);
        acc.y = fmaf(w, v.y, acc.y);
        acc.z = fmaf(w, v.z, acc.z);
        acc.w = fmaf(w, v.w, acc.w);
    }
    #pragma unroll
    for (int off = 16; off < 64; off <<= 1) {
        acc.x += __shfl_xor(acc.x, off);
        acc.y += __shfl_xor(acc.y, off);
        acc.z += __shfl_xor(acc.z, off);
        acc.w += __shfl_xor(acc.w, off);
    }
    if (eg == 0) {
        *reinterpret_cast<float4*>(&hout[((size_t)wave << 6) + (fl << 2)]) = acc;
    }
}

extern "C" void kernel_launch(void* const* d_in, const int* in_sizes, int n_in,
                              void* d_out, int out_size, void* d_ws, size_t ws_size,
                              hipStream_t stream) {
    const float* x   = (const float*)d_in[0];
    const float* ew  = (const float*)d_in[1];
    const int*   src = (const int*)d_in[2];
    const int*   dst = (const int*)d_in[3];
    float* out = (float*)d_out;

    // Workspace layout (~39.7 MB)
    float* hA         = (float*)d_ws;                       // N*D floats
    float* csr_w      = hA + (size_t)N_NODES * D_FEAT;      // E floats
    int*   csr_src    = (int*)(csr_w + N_EDGES);            // E ints
    int*   offsets    = csr_src + N_EDGES;                  // N+1 ints
    int*   cursor     = offsets + (N_NODES + 1);            // N ints
    int*   counts     = cursor + N_NODES;                   // N ints
    int*   blockSums  = counts + N_NODES;                   // NB_SCAN ints
    int*   blockPref  = blockSums + NB_SCAN;                // NB_SCAN ints

    k_zero<<<(N_NODES + 255) / 256, 256, 0, stream>>>(counts, N_NODES);
    k_hist<<<(N_EDGES + 255) / 256, 256, 0, stream>>>(dst, counts, N_EDGES);
    k_bsum<<<NB_SCAN, 256, 0, stream>>>(counts, blockSums, N_NODES);
    k_sscan<<<1, 512, 0, stream>>>(blockSums, blockPref, offsets, NB_SCAN, N_NODES);
    k_bscan<<<NB_SCAN, 256, 0, stream>>>(counts, blockPref, offsets, cursor, N_NODES);
    k_scatter<<<(N_EDGES + 255) / 256, 256, 0, stream>>>(src, dst, ew, cursor,
                                                         csr_src, csr_w, N_EDGES);

    const int prop_grid = (N_NODES * 64 + 255) / 256;
    const float* in = x;
    for (int k = 0; k < K_STEPS; ++k) {
        float* o = ((k & 1) == 0) ? hA : out;   // k=7 (last) writes d_out
        k_prop<<<prop_grid, 256, 0, stream>>>(in, o, offsets, csr_src, csr_w, N_NODES);
        in = o;
    }
}

// Round 3
// 651.469 us; speedup vs baseline: 2.4031x; 1.0621x over previous
//
#include <hip/hip_runtime.h>

#define N_NODES 100000
#define N_EDGES 1600000
#define D_FEAT  64
#define K_STEPS 8
#define NB_SCAN ((N_NODES + 255) / 256)   // 391 scan blocks

typedef unsigned long long u64;

__global__ void k_zero(int* __restrict__ p, int n) {
    int i = blockIdx.x * blockDim.x + threadIdx.x;
    if (i < n) p[i] = 0;
}

__global__ void k_hist(const int* __restrict__ dst, int* __restrict__ counts, int n) {
    int i = blockIdx.x * blockDim.x + threadIdx.x;
    if (i < n) atomicAdd(&counts[dst[i]], 1);
}

// Phase 1: per-block sum of 256 counts
__global__ void k_bsum(const int* __restrict__ counts, int* __restrict__ blockSums, int n) {
    __shared__ int ws[4];
    int t = threadIdx.x;
    int i = blockIdx.x * 256 + t;
    int c = (i < n) ? counts[i] : 0;
    for (int off = 32; off; off >>= 1) c += __shfl_down(c, off);
    if ((t & 63) == 0) ws[t >> 6] = c;
    __syncthreads();
    if (t == 0) blockSums[blockIdx.x] = ws[0] + ws[1] + ws[2] + ws[3];
}

// Phase 2: single block scans the 391 block sums -> exclusive blockPrefix
__global__ void k_sscan(const int* __restrict__ blockSums, int* __restrict__ blockPrefix,
                        int* __restrict__ offsets, int nb, int n) {
    __shared__ int sh[512];
    int t = threadIdx.x;
    int v = (t < nb) ? blockSums[t] : 0;
    sh[t] = v;
    __syncthreads();
    for (int off = 1; off < 512; off <<= 1) {
        int u = (t >= off) ? sh[t - off] : 0;
        __syncthreads();
        sh[t] += u;
        __syncthreads();
    }
    if (t < nb) blockPrefix[t] = sh[t] - v;   // exclusive
    if (t == 511) offsets[n] = sh[511];        // total == N_EDGES
}

// Phase 3: per-block exclusive scan of counts + block prefix -> offsets, cursor
__global__ void k_bscan(const int* __restrict__ counts, const int* __restrict__ blockPrefix,
                        int* __restrict__ offsets, int* __restrict__ cursor, int n) {
    __shared__ int sh[256];
    int t = threadIdx.x;
    int i = blockIdx.x * 256 + t;
    int c = (i < n) ? counts[i] : 0;
    sh[t] = c;
    __syncthreads();
    for (int off = 1; off < 256; off <<= 1) {
        int u = (t >= off) ? sh[t - off] : 0;
        __syncthreads();
        sh[t] += u;
        __syncthreads();
    }
    int excl = sh[t] - c + blockPrefix[blockIdx.x];
    if (i < n) { offsets[i] = excl; cursor[i] = excl; }
}

// One packed 8B (w<<32 | src) store per edge: halves scattered-line writebacks.
__global__ void k_scatter(const int* __restrict__ src, const int* __restrict__ dst,
                          const float* __restrict__ w, int* __restrict__ cursor,
                          u64* __restrict__ csr, int n) {
    int i = blockIdx.x * blockDim.x + threadIdx.x;
    if (i < n) {
        int d = dst[i];
        int pos = atomicAdd(&cursor[d], 1);
        u64 p = ((u64)__float_as_uint(w[i]) << 32) | (unsigned)src[i];
        csr[pos] = p;
    }
}

// One wave per node. lane = (edge_slot eg=lane>>3 [8 slots], feat_group fl=lane&7).
// Each lane gathers 2x float4 (32B) per edge; 8 edges in flight per iteration.
__global__ void k_prop(const float* __restrict__ hin, float* __restrict__ hout,
                       const int* __restrict__ offsets,
                       const u64* __restrict__ csr, int n) {
    int wave = (blockIdx.x * blockDim.x + threadIdx.x) >> 6;
    int lane = threadIdx.x & 63;
    if (wave >= n) return;
    int b = offsets[wave];
    int e = offsets[wave + 1];
    int eg = lane >> 3;        // edge slot 0..7
    int fl = lane & 7;         // feature group (8 floats each)
    float4 a0 = make_float4(0.f, 0.f, 0.f, 0.f);
    float4 a1 = make_float4(0.f, 0.f, 0.f, 0.f);
    for (int i = b + eg; i < e; i += 8) {
        u64 p   = csr[i];
        int s   = (int)(p & 0xffffffffu);
        float w = __uint_as_float((unsigned)(p >> 32));
        const float4* row = reinterpret_cast<const float4*>(&hin[((size_t)s << 6) + (fl << 3)]);
        float4 v0 = row[0];
        float4 v1 = row[1];
        a0.x = fmaf(w, v0.x, a0.x);
        a0.y = fmaf(w, v0.y, a0.y);
        a0.z = fmaf(w, v0.z, a0.z);
        a0.w = fmaf(w, v0.w, a0.w);
        a1.x = fmaf(w, v1.x, a1.x);
        a1.y = fmaf(w, v1.y, a1.y);
        a1.z = fmaf(w, v1.z, a1.z);
        a1.w = fmaf(w, v1.w, a1.w);
    }
    #pragma unroll
    for (int off = 8; off < 64; off <<= 1) {
        a0.x += __shfl_xor(a0.x, off);
        a0.y += __shfl_xor(a0.y, off);
        a0.z += __shfl_xor(a0.z, off);
        a0.w += __shfl_xor(a0.w, off);
        a1.x += __shfl_xor(a1.x, off);
        a1.y += __shfl_xor(a1.y, off);
        a1.z += __shfl_xor(a1.z, off);
        a1.w += __shfl_xor(a1.w, off);
    }
    if (eg == 0) {
        float4* o = reinterpret_cast<float4*>(&hout[((size_t)wave << 6) + (fl << 3)]);
        o[0] = a0;
        o[1] = a1;
    }
}

extern "C" void kernel_launch(void* const* d_in, const int* in_sizes, int n_in,
                              void* d_out, int out_size, void* d_ws, size_t ws_size,
                              hipStream_t stream) {
    const float* x   = (const float*)d_in[0];
    const float* ew  = (const float*)d_in[1];
    const int*   src = (const int*)d_in[2];
    const int*   dst = (const int*)d_in[3];
    float* out = (float*)d_out;

    // Workspace layout (~39.7 MB). hA is 6.4M floats (25.6MB, 8B-aligned end).
    float* hA         = (float*)d_ws;                        // N*D floats
    u64*   csr        = (u64*)(hA + (size_t)N_NODES * D_FEAT);  // E x 8B packed (src,w)
    int*   offsets    = (int*)(csr + N_EDGES);               // N+1 ints
    int*   cursor     = offsets + (N_NODES + 1);             // N ints
    int*   counts     = cursor + N_NODES;                    // N ints
    int*   blockSums  = counts + N_NODES;                    // NB_SCAN ints
    int*   blockPref  = blockSums + NB_SCAN;                 // NB_SCAN ints

    k_zero<<<(N_NODES + 255) / 256, 256, 0, stream>>>(counts, N_NODES);
    k_hist<<<(N_EDGES + 255) / 256, 256, 0, stream>>>(dst, counts, N_EDGES);
    k_bsum<<<NB_SCAN, 256, 0, stream>>>(counts, blockSums, N_NODES);
    k_sscan<<<1, 512, 0, stream>>>(blockSums, blockPref, offsets, NB_SCAN, N_NODES);
    k_bscan<<<NB_SCAN, 256, 0, stream>>>(counts, blockPref, offsets, cursor, N_NODES);
    k_scatter<<<(N_EDGES + 255) / 256, 256, 0, stream>>>(src, dst, ew, cursor, csr, N_EDGES);

    const int prop_grid = (N_NODES * 64 + 255) / 256;
    const float* in = x;
    for (int k = 0; k < K_STEPS; ++k) {
        float* o = ((k & 1) == 0) ? hA : out;   // k=7 (last) writes d_out
        k_prop<<<prop_grid, 256, 0, stream>>>(in, o, offsets, csr, N_NODES);
        in = o;
    }
}

// Round 4
// 615.794 us; speedup vs baseline: 2.5423x; 1.0579x over previous
//
#include <hip/hip_runtime.h>

#define N_NODES 100000
#define N_EDGES 1600000
#define D_FEAT  64
#define K_STEPS 8
#define NB_SCAN ((N_NODES + 255) / 256)   // 391 scan blocks

typedef unsigned long long u64;
typedef float f4 __attribute__((ext_vector_type(4)));

__global__ void k_zero(int* __restrict__ p, int n) {
    int i = blockIdx.x * blockDim.x + threadIdx.x;
    if (i < n) p[i] = 0;
}

// Histogram AND per-edge rank within its dst list.
// Rank order is nondeterministic across runs but the sum is commutative;
// error stays at ulp level (measured 2.4e-7 vs 1.5e-6 threshold).
__global__ void k_hist(const int* __restrict__ dst, int* __restrict__ counts,
                       int* __restrict__ rank, int n) {
    int i = blockIdx.x * blockDim.x + threadIdx.x;
    if (i < n) rank[i] = atomicAdd(&counts[dst[i]], 1);
}

// Phase 1: per-block sum of 256 counts
__global__ void k_bsum(const int* __restrict__ counts, int* __restrict__ blockSums, int n) {
    __shared__ int ws[4];
    int t = threadIdx.x;
    int i = blockIdx.x * 256 + t;
    int c = (i < n) ? counts[i] : 0;
    for (int off = 32; off; off >>= 1) c += __shfl_down(c, off);
    if ((t & 63) == 0) ws[t >> 6] = c;
    __syncthreads();
    if (t == 0) blockSums[blockIdx.x] = ws[0] + ws[1] + ws[2] + ws[3];
}

// Phase 2: single block scans the 391 block sums -> exclusive blockPrefix
__global__ void k_sscan(const int* __restrict__ blockSums, int* __restrict__ blockPrefix,
                        int* __restrict__ offsets, int nb, int n) {
    __shared__ int sh[512];
    int t = threadIdx.x;
    int v = (t < nb) ? blockSums[t] : 0;
    sh[t] = v;
    __syncthreads();
    for (int off = 1; off < 512; off <<= 1) {
        int u = (t >= off) ? sh[t - off] : 0;
        __syncthreads();
        sh[t] += u;
        __syncthreads();
    }
    if (t < nb) blockPrefix[t] = sh[t] - v;   // exclusive
    if (t == 511) offsets[n] = sh[511];        // total == N_EDGES
}

// Phase 3: per-block exclusive scan of counts + block prefix -> offsets
__global__ void k_bscan(const int* __restrict__ counts, const int* __restrict__ blockPrefix,
                        int* __restrict__ offsets, int n) {
    __shared__ int sh[256];
    int t = threadIdx.x;
    int i = blockIdx.x * 256 + t;
    int c = (i < n) ? counts[i] : 0;
    sh[t] = c;
    __syncthreads();
    for (int off = 1; off < 256; off <<= 1) {
        int u = (t >= off) ? sh[t - off] : 0;
        __syncthreads();
        sh[t] += u;
        __syncthreads();
    }
    int excl = sh[t] - c + blockPrefix[blockIdx.x];
    if (i < n) offsets[i] = excl;
}

// Atomic-free scatter: pos = offsets[dst] + rank. One nt 8B packed store per edge.
__global__ void k_scatter(const int* __restrict__ src, const int* __restrict__ dst,
                          const float* __restrict__ w, const int* __restrict__ offsets,
                          const int* __restrict__ rank, u64* __restrict__ csr, int n) {
    int i = blockIdx.x * blockDim.x + threadIdx.x;
    if (i < n) {
        int d = dst[i];
        int pos = offsets[d] + rank[i];
        u64 p = ((u64)__float_as_uint(w[i]) << 32) | (unsigned)src[i];
        __builtin_nontemporal_store(p, &csr[pos]);
    }
}

// One wave per node. lane = (edge_slot eg=lane>>3 [8 slots], feat_group fl=lane&7).
// Each lane gathers 2x float4 (32B) per edge; 8 edges in flight per iteration.
// CSR loads and output stores are non-temporal to keep h resident in L2.
__global__ void k_prop(const float* __restrict__ hin, float* __restrict__ hout,
                       const int* __restrict__ offsets,
                       const u64* __restrict__ csr, int n) {
    int wave = (blockIdx.x * blockDim.x + threadIdx.x) >> 6;
    int lane = threadIdx.x & 63;
    if (wave >= n) return;
    int b = offsets[wave];
    int e = offsets[wave + 1];
    int eg = lane >> 3;        // edge slot 0..7
    int fl = lane & 7;         // feature group (8 floats each)
    f4 a0 = {0.f, 0.f, 0.f, 0.f};
    f4 a1 = {0.f, 0.f, 0.f, 0.f};
    for (int i = b + eg; i < e; i += 8) {
        u64 p   = __builtin_nontemporal_load(&csr[i]);
        int s   = (int)(p & 0xffffffffu);
        float w = __uint_as_float((unsigned)(p >> 32));
        const f4* row = reinterpret_cast<const f4*>(&hin[((size_t)s << 6) + (fl << 3)]);
        f4 v0 = row[0];
        f4 v1 = row[1];
        a0.x = fmaf(w, v0.x, a0.x);
        a0.y = fmaf(w, v0.y, a0.y);
        a0.z = fmaf(w, v0.z, a0.z);
        a0.w = fmaf(w, v0.w, a0.w);
        a1.x = fmaf(w, v1.x, a1.x);
        a1.y = fmaf(w, v1.y, a1.y);
        a1.z = fmaf(w, v1.z, a1.z);
        a1.w = fmaf(w, v1.w, a1.w);
    }
    #pragma unroll
    for (int off = 8; off < 64; off <<= 1) {
        a0.x += __shfl_xor(a0.x, off);
        a0.y += __shfl_xor(a0.y, off);
        a0.z += __shfl_xor(a0.z, off);
        a0.w += __shfl_xor(a0.w, off);
        a1.x += __shfl_xor(a1.x, off);
        a1.y += __shfl_xor(a1.y, off);
        a1.z += __shfl_xor(a1.z, off);
        a1.w += __shfl_xor(a1.w, off);
    }
    if (eg == 0) {
        f4* o = reinterpret_cast<f4*>(&hout[((size_t)wave << 6) + (fl << 3)]);
        __builtin_nontemporal_store(a0, &o[0]);
        __builtin_nontemporal_store(a1, &o[1]);
    }
}

extern "C" void kernel_launch(void* const* d_in, const int* in_sizes, int n_in,
                              void* d_out, int out_size, void* d_ws, size_t ws_size,
                              hipStream_t stream) {
    const float* x   = (const float*)d_in[0];
    const float* ew  = (const float*)d_in[1];
    const int*   src = (const int*)d_in[2];
    const int*   dst = (const int*)d_in[3];
    float* out = (float*)d_out;

    // Workspace layout (~39.7 MB). rank[] aliases hA: rank is consumed by
    // k_scatter, which completes before the first k_prop writes hA.
    float* hA         = (float*)d_ws;                           // N*D floats
    int*   rank       = (int*)d_ws;                             // E ints (aliases hA)
    u64*   csr        = (u64*)(hA + (size_t)N_NODES * D_FEAT);  // E x 8B packed (src,w)
    int*   offsets    = (int*)(csr + N_EDGES);                  // N+1 ints
    int*   counts     = offsets + (N_NODES + 1);                // N ints
    int*   blockSums  = counts + N_NODES;                       // NB_SCAN ints
    int*   blockPref  = blockSums + NB_SCAN;                    // NB_SCAN ints

    k_zero<<<(N_NODES + 255) / 256, 256, 0, stream>>>(counts, N_NODES);
    k_hist<<<(N_EDGES + 255) / 256, 256, 0, stream>>>(dst, counts, rank, N_EDGES);
    k_bsum<<<NB_SCAN, 256, 0, stream>>>(counts, blockSums, N_NODES);
    k_sscan<<<1, 512, 0, stream>>>(blockSums, blockPref, offsets, NB_SCAN, N_NODES);
    k_bscan<<<NB_SCAN, 256, 0, stream>>>(counts, blockPref, offsets, N_NODES);
    k_scatter<<<(N_EDGES + 255) / 256, 256, 0, stream>>>(src, dst, ew, offsets, rank,
                                                         csr, N_EDGES);

    const int prop_grid = (N_NODES * 64 + 255) / 256;
    const float* in = x;
    for (int k = 0; k < K_STEPS; ++k) {
        float* o = ((k & 1) == 0) ? hA : out;   // k=7 (last) writes d_out
        k_prop<<<prop_grid, 256, 0, stream>>>(in, o, offsets, csr, N_NODES);
        in = o;
    }
}

// Round 5
// 612.365 us; speedup vs baseline: 2.5565x; 1.0056x over previous
//
#include <hip/hip_runtime.h>

#define N_NODES 100000
#define N_EDGES 1600000
#define D_FEAT  64
#define K_STEPS 8
#define NB_SCAN ((N_NODES + 255) / 256)   // 391 scan blocks
#define TILES   16
#define TILE_W  6250                       // 16 * 6250 = 100000 exactly

typedef unsigned long long u64;
typedef float f4 __attribute__((ext_vector_type(4)));

__device__ __forceinline__ int src_tile(int s) { return (int)((unsigned)s / (unsigned)TILE_W); }

__global__ void k_zero(int* __restrict__ p, int n) {
    int i = blockIdx.x * blockDim.x + threadIdx.x;
    if (i < n) p[i] = 0;
}

// Histogram into (src-tile, dst) buckets; atomic return = rank within bucket.
// Bucket order is nondeterministic across runs but the sum is commutative.
__global__ void k_hist(const int* __restrict__ dst, const int* __restrict__ src,
                       int* __restrict__ cnt16, int* __restrict__ rank, int n) {
    int i = blockIdx.x * blockDim.x + threadIdx.x;
    if (i < n) {
        int t = src_tile(src[i]);
        rank[i] = atomicAdd(&cnt16[t * N_NODES + dst[i]], 1);
    }
}

// Per-node: exclusive prefix over the 16 tile buckets -> tilePre, total -> counts.
__global__ void k_tilescan(const int* __restrict__ cnt16, int* __restrict__ tilePre,
                           int* __restrict__ counts, int n) {
    int v = blockIdx.x * blockDim.x + threadIdx.x;
    if (v >= n) return;
    int run = 0;
    #pragma unroll
    for (int t = 0; t < TILES; ++t) {
        int c = cnt16[t * N_NODES + v];
        tilePre[t * N_NODES + v] = run;
        run += c;
    }
    counts[v] = run;
}

// Phase 1: per-block sum of 256 counts
__global__ void k_bsum(const int* __restrict__ counts, int* __restrict__ blockSums, int n) {
    __shared__ int ws[4];
    int t = threadIdx.x;
    int i = blockIdx.x * 256 + t;
    int c = (i < n) ? counts[i] : 0;
    for (int off = 32; off; off >>= 1) c += __shfl_down(c, off);
    if ((t & 63) == 0) ws[t >> 6] = c;
    __syncthreads();
    if (t == 0) blockSums[blockIdx.x] = ws[0] + ws[1] + ws[2] + ws[3];
}

// Phase 2: single block scans the 391 block sums -> exclusive blockPrefix
__global__ void k_sscan(const int* __restrict__ blockSums, int* __restrict__ blockPrefix,
                        int* __restrict__ offsets, int nb, int n) {
    __shared__ int sh[512];
    int t = threadIdx.x;
    int v = (t < nb) ? blockSums[t] : 0;
    sh[t] = v;
    __syncthreads();
    for (int off = 1; off < 512; off <<= 1) {
        int u = (t >= off) ? sh[t - off] : 0;
        __syncthreads();
        sh[t] += u;
        __syncthreads();
    }
    if (t < nb) blockPrefix[t] = sh[t] - v;   // exclusive
    if (t == 511) offsets[n] = sh[511];        // total == N_EDGES
}

// Phase 3: per-block exclusive scan of counts + block prefix -> offsets
__global__ void k_bscan(const int* __restrict__ counts, const int* __restrict__ blockPrefix,
                        int* __restrict__ offsets, int n) {
    __shared__ int sh[256];
    int t = threadIdx.x;
    int i = blockIdx.x * 256 + t;
    int c = (i < n) ? counts[i] : 0;
    sh[t] = c;
    __syncthreads();
    for (int off = 1; off < 256; off <<= 1) {
        int u = (t >= off) ? sh[t - off] : 0;
        __syncthreads();
        sh[t] += u;
        __syncthreads();
    }
    int excl = sh[t] - c + blockPrefix[blockIdx.x];
    if (i < n) offsets[i] = excl;
}

// Atomic-free scatter: pos = offsets[dst] + tilePre[tile][dst] + rank.
__global__ void k_scatter(const int* __restrict__ src, const int* __restrict__ dst,
                          const float* __restrict__ w, const int* __restrict__ offsets,
                          const int* __restrict__ tilePre, const int* __restrict__ rank,
                          u64* __restrict__ csr, int n) {
    int i = blockIdx.x * blockDim.x + threadIdx.x;
    if (i < n) {
        int s = src[i];
        int d = dst[i];
        int t = src_tile(s);
        int pos = offsets[d] + tilePre[t * N_NODES + d] + rank[i];
        u64 p = ((u64)__float_as_uint(w[i]) << 32) | (unsigned)s;
        __builtin_nontemporal_store(p, &csr[pos]);
    }
}

// One wave per node. lane = (edge_slot eg=lane>>3 [8 slots], feat_group fl=lane&7).
// Each lane gathers 2x float4 (32B) per edge; 8 edges in flight per iteration.
// Edge lists are grouped by src-tile -> concurrent waves gather from the same
// ~1.6MB h-slab, which fits each XCD's private L2.
__global__ void k_prop(const float* __restrict__ hin, float* __restrict__ hout,
                       const int* __restrict__ offsets,
                       const u64* __restrict__ csr, int n) {
    int wave = (blockIdx.x * blockDim.x + threadIdx.x) >> 6;
    int lane = threadIdx.x & 63;
    if (wave >= n) return;
    int b = offsets[wave];
    int e = offsets[wave + 1];
    int eg = lane >> 3;        // edge slot 0..7
    int fl = lane & 7;         // feature group (8 floats each)
    f4 a0 = {0.f, 0.f, 0.f, 0.f};
    f4 a1 = {0.f, 0.f, 0.f, 0.f};
    for (int i = b + eg; i < e; i += 8) {
        u64 p   = __builtin_nontemporal_load(&csr[i]);
        int s   = (int)(p & 0xffffffffu);
        float w = __uint_as_float((unsigned)(p >> 32));
        const f4* row = reinterpret_cast<const f4*>(&hin[((size_t)s << 6) + (fl << 3)]);
        f4 v0 = row[0];
        f4 v1 = row[1];
        a0.x = fmaf(w, v0.x, a0.x);
        a0.y = fmaf(w, v0.y, a0.y);
        a0.z = fmaf(w, v0.z, a0.z);
        a0.w = fmaf(w, v0.w, a0.w);
        a1.x = fmaf(w, v1.x, a1.x);
        a1.y = fmaf(w, v1.y, a1.y);
        a1.z = fmaf(w, v1.z, a1.z);
        a1.w = fmaf(w, v1.w, a1.w);
    }
    #pragma unroll
    for (int off = 8; off < 64; off <<= 1) {
        a0.x += __shfl_xor(a0.x, off);
        a0.y += __shfl_xor(a0.y, off);
        a0.z += __shfl_xor(a0.z, off);
        a0.w += __shfl_xor(a0.w, off);
        a1.x += __shfl_xor(a1.x, off);
        a1.y += __shfl_xor(a1.y, off);
        a1.z += __shfl_xor(a1.z, off);
        a1.w += __shfl_xor(a1.w, off);
    }
    if (eg == 0) {
        f4* o = reinterpret_cast<f4*>(&hout[((size_t)wave << 6) + (fl << 3)]);
        o[0] = a0;
        o[1] = a1;
    }
}

extern "C" void kernel_launch(void* const* d_in, const int* in_sizes, int n_in,
                              void* d_out, int out_size, void* d_ws, size_t ws_size,
                              hipStream_t stream) {
    const float* x   = (const float*)d_in[0];
    const float* ew  = (const float*)d_in[1];
    const int*   src = (const int*)d_in[2];
    const int*   dst = (const int*)d_in[3];
    float* out = (float*)d_out;

    // Workspace (~39.7 MB). rank/cnt16/tilePre alias hA: all are dead before
    // the first k_prop writes hA (3 x 1.6M ints = 19.2MB <= hA's 25.6MB).
    float* hA         = (float*)d_ws;                            // N*D floats
    int*   rank       = (int*)d_ws;                              // E ints
    int*   cnt16      = rank + N_EDGES;                          // TILES*N ints (=E)
    int*   tilePre    = cnt16 + TILES * N_NODES;                 // TILES*N ints (=E)
    u64*   csr        = (u64*)(hA + (size_t)N_NODES * D_FEAT);   // E x 8B packed (src,w)
    int*   offsets    = (int*)(csr + N_EDGES);                   // N+1 ints
    int*   counts     = offsets + (N_NODES + 1);                 // N ints
    int*   blockSums  = counts + N_NODES;                        // NB_SCAN ints
    int*   blockPref  = blockSums + NB_SCAN;                     // NB_SCAN ints

    k_zero<<<(TILES * N_NODES + 255) / 256, 256, 0, stream>>>(cnt16, TILES * N_NODES);
    k_hist<<<(N_EDGES + 255) / 256, 256, 0, stream>>>(dst, src, cnt16, rank, N_EDGES);
    k_tilescan<<<(N_NODES + 255) / 256, 256, 0, stream>>>(cnt16, tilePre, counts, N_NODES);
    k_bsum<<<NB_SCAN, 256, 0, stream>>>(counts, blockSums, N_NODES);
    k_sscan<<<1, 512, 0, stream>>>(blockSums, blockPref, offsets, NB_SCAN, N_NODES);
    k_bscan<<<NB_SCAN, 256, 0, stream>>>(counts, blockPref, offsets, N_NODES);
    k_scatter<<<(N_EDGES + 255) / 256, 256, 0, stream>>>(src, dst, ew, offsets, tilePre,
                                                         rank, csr, N_EDGES);

    const int prop_grid = (N_NODES * 64 + 255) / 256;
    const float* in = x;
    for (int k = 0; k < K_STEPS; ++k) {
        float* o = ((k & 1) == 0) ? hA : out;   // k=7 (last) writes d_out
        k_prop<<<prop_grid, 256, 0, stream>>>(in, o, offsets, csr, N_NODES);
        in = o;
    }
}